// Round 12
// baseline (98.451 us; speedup 1.0000x reference)
//
#include <hip/hip_runtime.h>
#include <math.h>

#define BATCH  8192
#define DIM    128
#define NTREES 512
#define UNITS  8
#define RB 64                      // batch rows per row-block
#define NTB 16                     // tree-blocks of 32 trees
#define NBXG 64                    // bx-groups of 2 row-blocks

typedef __attribute__((ext_vector_type(8))) __bf16 bf16x8;
typedef __attribute__((ext_vector_type(4))) float f32x4;
typedef __attribute__((ext_vector_type(2))) float f32x2;
typedef __attribute__((ext_vector_type(4))) unsigned int u32x4;

static __device__ inline unsigned short f2bf(float v) {
  __bf16 h = (__bf16)v;
  return *(unsigned short*)&h;
}

// pack two f32 -> one dword of 2 bf16 (src0 -> [15:0], src1 -> [31:16])
static __device__ inline unsigned cvtpk(f32x2 v) {
  unsigned r;
  asm("v_cvt_pk_bf16_f32 %0, %1, %2" : "=v"(r) : "v"(v[0]), "v"(v[1]));
  return r;
}

// ---------------------------------------------------------------------------
// Fused prep (round-8 layout, unchanged numerics) + ticket-counter zeroing.
//  [0,4096):     sparsemax per (tree,d) -> Wfrag A-fragment stream (S = t>>2)
//  [4096,12288): inputs -> bf16 row-swizzled Ximg   (b==4096 also zeros cnt)
//  [12288,16384): response -> Rb B-fragment stream
// ---------------------------------------------------------------------------
__global__ __launch_bounds__(128) void prep_all(
    const float* __restrict__ logits, const float* __restrict__ thr,
    const float* __restrict__ logtemp, const float* __restrict__ inputs,
    const float* __restrict__ resp,
    unsigned short* __restrict__ Wfrag, unsigned short* __restrict__ Ximg,
    unsigned short* __restrict__ Rb, float* __restrict__ biasPad,
    int* __restrict__ cnt)
{
  const int b = blockIdx.x, tid = threadIdx.x;
  if (b < 4096) {
    const int t = b >> 3, d = b & 7;
    const int S = t >> 2, tq = t & 3;
    const int p = d >> 2, dloc = d & 3;
    const int ln = tq * 4 + dloc;
    const int ks = tid >> 5, G = (tid >> 3) & 3, j = tid & 7;
    const int lane = G * 16 + ln;
    const size_t wi = ((size_t)((S * 2 + p) * 4 + ks) * 64 + lane) * 8 + j;
    if (d >= 6) {
      Wfrag[wi] = 0;
      if (tid == 0) biasPad[t * 8 + d] = 0.f;
      return;
    }
    __shared__ __align__(16) float z[128];
    __shared__ float rc[128], rs[128];
    float zi = logits[((size_t)tid * NTREES + t) * 6 + d];
    z[tid] = zi;
    __syncthreads();
    float k = 0.f, Ssum = 0.f;
    const float4* z4 = (const float4*)z;
    #pragma unroll 4
    for (int q = 0; q < 32; ++q) {
      float4 v = z4[q];
      if (v.x >= zi) { k += 1.f; Ssum += v.x; }
      if (v.y >= zi) { k += 1.f; Ssum += v.y; }
      if (v.z >= zi) { k += 1.f; Ssum += v.z; }
      if (v.w >= zi) { k += 1.f; Ssum += v.w; }
    }
    bool sup = (1.f + k * zi) > Ssum;
    rc[tid] = sup ? 1.f : 0.f;
    rs[tid] = sup ? zi : 0.f;
    __syncthreads();
    for (int off = 64; off > 0; off >>= 1) {
      if (tid < off) { rc[tid] += rc[tid + off]; rs[tid] += rs[tid + off]; }
      __syncthreads();
    }
    float tau = (rs[0] - 1.f) / rc[0];
    float et = expf(-logtemp[t*6 + d]);
    Wfrag[wi] = f2bf(fmaxf(zi - tau, 0.f) * et);
    if (tid == 0) biasPad[t*8 + d] = -thr[t*6 + d] * et;
  } else if (b < 12288) {
    const int r = b - 4096;
    if (b == 4096 && tid < NBXG) cnt[tid] = 0;      // zero tickets each launch
    float v = inputs[(size_t)r * DIM + tid];
    int col = ((tid * 2) ^ ((r & 7) << 4)) >> 1;
    Ximg[(size_t)r * DIM + col] = f2bf(v);
  } else {
    const int idx = (b - 12288) * 128 + tid;         // < 524288
    const int j = idx & 7, lane = (idx >> 3) & 63;
    const int ks = (idx >> 9) & 3, half = (idx >> 11) & 1, S = idx >> 12;
    const int G = lane >> 4, u = lane & 15;
    const int tree = S * 4 + G;
    const int leaf = j | (ks << 3) | (half << 5);
    float v = (u < UNITS) ? resp[((size_t)tree*UNITS + u)*64 + leaf] : 0.f;
    Rb[idx] = f2bf(v);
  }
}

// ---------------------------------------------------------------------------
// Main: 2 row-blocks (128 rows) x 32 trees per block, 4 waves, grid 1024.
// tb = (wg&7)*2 + ((wg>>3)&1) -> each XCD owns 2 tree-blocks (L2 set:
// Ximg 2MB + 2x128KB frag slices < 4MB).  Per sub: load Afr/B2 once, use
// for BOTH row-blocks (fragment L2 traffic halved vs round 8).  Final
// tree-block reduction fused via device-fence + atomic ticket: the 16th
// block per bx-group sums partial[0..15] in fixed order (deterministic).
// ---------------------------------------------------------------------------
__global__ __launch_bounds__(256, 3) void odt_main(
    const unsigned short* __restrict__ Ximg, const unsigned short* __restrict__ Wfrag,
    const float* __restrict__ biasPad, const unsigned short* __restrict__ Rb,
    float* __restrict__ partial, int* __restrict__ cnt, float* __restrict__ out)
{
  __shared__ __align__(16) char pool[33808];
  char* Xl = pool;                        // 32768 B (2 row-block tiles)
  float* biasl = (float*)(pool + 32768);  // 1024 B (256 floats)
  int* tick    = (int*)(pool + 33792);
  float* red   = (float*)pool;            // aliases Xl after compute (8 KB)

  const int tid = threadIdx.x;
  const int lane = tid & 63;
  const int w = tid >> 6;       // wave 0..3
  const int G = lane >> 4;      // 0..3 == this lane's tree within the quad
  const int ln = lane & 15;

  const int wg = blockIdx.x;
  const int tb  = (wg & 7) * 2 + ((wg >> 3) & 1);   // 0..15, XCD-grouped
  const int bxg = wg >> 4;                          // 0..63
  const int bx0 = bxg * 2;

  // stage both X tiles (32KB, already bf16+swizzled in Ximg, contiguous)
  {
    const float4* src = (const float4*)(Ximg + (size_t)bx0 * RB * DIM);
    float4* dst = (float4*)Xl;
    #pragma unroll
    for (int it = 0; it < 8; ++it) dst[tid + it * 256] = src[tid + it * 256];
  }
  biasl[tid & 255] = biasPad[(size_t)tb * 256 + (tid & 255)];
  __syncthreads();

  // swizzled X read addresses ((nt*16+ln)&7 == ln&7); tile offset added later
  const char* xbase[4];
  #pragma unroll
  for (int ks = 0; ks < 4; ++ks)
    xbase[ks] = Xl + ln*256 + ((ks*64 + G*16) ^ ((ln & 7) << 4));

  f32x4 out_[2][4];
  #pragma unroll
  for (int bxq = 0; bxq < 2; ++bxq)
    #pragma unroll
    for (int nt = 0; nt < 4; ++nt)
      #pragma unroll
      for (int r = 0; r < 4; ++r) out_[bxq][nt][r] = 0.f;

  const f32x2 ch = (f32x2){0.5f, -0.5f};

  #pragma unroll 1
  for (int sub = 0; sub < 2; ++sub) {
    const int S = tb*8 + sub*4 + w;
    const bf16x8* wf = (const bf16x8*)Wfrag + (size_t)S * 8 * 64;
    const bf16x8* rb = (const bf16x8*)Rb   + (size_t)S * 8 * 64;
    bf16x8 Afr[2][4], B2[2][4];
    #pragma unroll
    for (int p = 0; p < 2; ++p)
      #pragma unroll
      for (int ks = 0; ks < 4; ++ks) {
        Afr[p][ks] = wf[(p*4 + ks)*64 + lane];
        B2[p][ks]  = rb[(p*4 + ks)*64 + lane];
      }
    const int tl8 = ((sub*4 + w)*4 + G) * 8;
    f32x2 bb[6];
    #pragma unroll
    for (int d = 0; d < 6; ++d) {
      float bvd = biasl[tl8 + d];
      bb[d] = (f32x2){0.5f + 0.5f*bvd, 0.5f - 0.5f*bvd};
    }

    #pragma unroll
    for (int bxq = 0; bxq < 2; ++bxq) {
      #pragma unroll
      for (int nt = 0; nt < 4; ++nt) {
        bf16x8 Bfr[4];
        #pragma unroll
        for (int ks = 0; ks < 4; ++ks)
          Bfr[ks] = *(const bf16x8*)(xbase[ks] + bxq*16384 + nt*4096);
        f32x4 c1[2];
        #pragma unroll
        for (int p = 0; p < 2; ++p)
          #pragma unroll
          for (int r = 0; r < 4; ++r) c1[p][r] = 0.f;
        #pragma unroll
        for (int ks = 0; ks < 4; ++ks)
          c1[0] = __builtin_amdgcn_mfma_f32_16x16x32_bf16(Afr[0][ks], Bfr[ks], c1[0], 0,0,0);
        #pragma unroll
        for (int ks = 0; ks < 4; ++ks)
          c1[1] = __builtin_amdgcn_mfma_f32_16x16x32_bf16(Afr[1][ks], Bfr[ks], c1[1], 0,0,0);

        // gates as {s, om} pairs: P = clamp01(fd*{0.5,-0.5} + bb)
        f32x2 P[6];
        #pragma unroll
        for (int d = 0; d < 6; ++d) {
          float fdv = (d < 4) ? c1[0][d] : c1[1][d-4];
          f32x2 t = fdv*ch + bb[d];
          P[d] = __builtin_elementwise_min(
                   __builtin_elementwise_max(t, (f32x2)0.f), (f32x2)1.f);
        }
        // leaf bits: j->d0-2, ks&1->d3, ks>>1->d4, half->d5
        f32x2 qA = P[0]*P[1][0], qB = P[0]*P[1][1];
        f32x2 p3a = qA*P[2][0], p3b = qB*P[2][0];
        f32x2 p3c = qA*P[2][1], p3d = qB*P[2][1];
        f32x2 c34A = P[3]*P[4][0];
        f32x2 c34B = P[3]*P[4][1];

        #pragma unroll
        for (int h = 0; h < 2; ++h) {
          f32x2 ccA = c34A*P[5][h], ccB = c34B*P[5][h];
          float cc[4] = { ccA[0], ccA[1], ccB[0], ccB[1] };
          #pragma unroll
          for (int ks = 0; ks < 4; ++ks) {
            float c = cc[ks];
            u32x4 aw;
            aw[0] = cvtpk(p3a*c);
            aw[1] = cvtpk(p3b*c);
            aw[2] = cvtpk(p3c*c);
            aw[3] = cvtpk(p3d*c);
            bf16x8 A = __builtin_bit_cast(bf16x8, aw);
            out_[bxq][nt] = __builtin_amdgcn_mfma_f32_16x16x32_bf16(A, B2[h][ks], out_[bxq][nt], 0,0,0);
          }
        }
      }
    }
  }

  // ---- cross-wave reduction per row-block (red aliases Xl; Xl dead) ----
  #pragma unroll
  for (int bxq = 0; bxq < 2; ++bxq) {
    __syncthreads();
    if (ln < UNITS) {
      #pragma unroll
      for (int nt = 0; nt < 4; ++nt)
        #pragma unroll
        for (int r = 0; r < 4; ++r)
          red[w*512 + (nt*16 + 4*G + r)*8 + ln] = out_[bxq][nt][r];
    }
    __syncthreads();
    #pragma unroll
    for (int v = 0; v < 2; ++v) {
      int e = tid + v*256;             // 0..511 = row*8+u
      float sum = red[0*512 + e] + red[1*512 + e]
                + red[2*512 + e] + red[3*512 + e];
      partial[((size_t)tb*128 + bx0 + bxq)*512 + e] = sum;
    }
  }

  // ---- fused tree-block reduction: fence + ticket, last block sums ----
  __syncthreads();                     // drains partial stores (waitcnt+bar)
  if (tid == 0) {
    __threadfence();                   // device-scope writeback
    *tick = atomicAdd(&cnt[bxg], 1);
  }
  __syncthreads();
  if (*tick == NTB - 1) {
    __threadfence();                   // acquire before reading remote partials
    #pragma unroll
    for (int v = 0; v < 4; ++v) {
      int e = tid + v*256;             // 0..1023 = bxq*512 + row*8+u
      int bx = bx0 + (e >> 9), re = e & 511;
      float sum = 0.f;
      #pragma unroll
      for (int t16 = 0; t16 < NTB; ++t16)
        sum += partial[((size_t)t16*128 + bx)*512 + re];
      out[(size_t)bx*512 + re] = sum * (1.f/NTREES);
    }
  }
}

extern "C" void kernel_launch(void* const* d_in, const int* in_sizes, int n_in,
                              void* d_out, int out_size, void* d_ws, size_t ws_size,
                              hipStream_t stream)
{
  const float* inputs   = (const float*)d_in[0];
  const float* logits   = (const float*)d_in[1];
  const float* thr      = (const float*)d_in[2];
  const float* logtemp  = (const float*)d_in[3];
  const float* response = (const float*)d_in[4];
  float* out = (float*)d_out;

  char* ws = (char*)d_ws;
  unsigned short* Wfrag = (unsigned short*)(ws);                // 1 MB
  unsigned short* Ximg  = (unsigned short*)(ws + (1<<20));      // 2 MB
  unsigned short* Rb    = (unsigned short*)(ws + (3<<20));      // 1 MB
  float* biasPad        = (float*)(ws + (4<<20));               // 16 KB
  int* cnt              = (int*)(ws + (4<<20) + (1<<14));       // 256 B
  float* partial        = (float*)(ws + (4<<20) + (1<<15));     // 4 MB

  hipLaunchKernelGGL(prep_all, dim3(16384), dim3(128), 0, stream,
                     logits, thr, logtemp, inputs, response,
                     Wfrag, Ximg, Rb, biasPad, cnt);
  hipLaunchKernelGGL(odt_main, dim3(NTB * NBXG), dim3(256), 0, stream,
                     Ximg, Wfrag, biasPad, Rb, partial, cnt, out);
}

// Round 13
// 54.523 us; speedup vs baseline: 1.8057x; 1.8057x over previous
//
#include <hip/hip_runtime.h>
#include <math.h>

#define BATCH  8192
#define DIM    128
#define NTREES 512
#define UNITS  8
#define RB 64                      // batch rows per row-block
#define NTB 16                     // tree-blocks of 32 trees
#define NBXG 64                    // bx-groups of 2 row-blocks

typedef __attribute__((ext_vector_type(8))) __bf16 bf16x8;
typedef __attribute__((ext_vector_type(4))) float f32x4;
typedef __attribute__((ext_vector_type(2))) float f32x2;
typedef __attribute__((ext_vector_type(4))) unsigned int u32x4;

static __device__ inline unsigned short f2bf(float v) {
  __bf16 h = (__bf16)v;
  return *(unsigned short*)&h;
}

// pack two f32 -> one dword of 2 bf16 (src0 -> [15:0], src1 -> [31:16])
static __device__ inline unsigned cvtpk(f32x2 v) {
  unsigned r;
  asm("v_cvt_pk_bf16_f32 %0, %1, %2" : "=v"(r) : "v"(v[0]), "v"(v[1]));
  return r;
}

// ---------------------------------------------------------------------------
// Fused prep (identical numerics to rounds 8-12):
//  [0,4096):     sparsemax per (tree,d) -> Wfrag A-fragment stream (S = t>>2)
//  [4096,12288): inputs -> bf16 row-swizzled Ximg
//  [12288,16384): response -> Rb B-fragment stream
// ---------------------------------------------------------------------------
__global__ __launch_bounds__(128) void prep_all(
    const float* __restrict__ logits, const float* __restrict__ thr,
    const float* __restrict__ logtemp, const float* __restrict__ inputs,
    const float* __restrict__ resp,
    unsigned short* __restrict__ Wfrag, unsigned short* __restrict__ Ximg,
    unsigned short* __restrict__ Rb, float* __restrict__ biasPad)
{
  const int b = blockIdx.x, tid = threadIdx.x;
  if (b < 4096) {
    const int t = b >> 3, d = b & 7;
    const int S = t >> 2, tq = t & 3;
    const int p = d >> 2, dloc = d & 3;
    const int ln = tq * 4 + dloc;
    const int ks = tid >> 5, G = (tid >> 3) & 3, j = tid & 7;
    const int lane = G * 16 + ln;
    const size_t wi = ((size_t)((S * 2 + p) * 4 + ks) * 64 + lane) * 8 + j;
    if (d >= 6) {
      Wfrag[wi] = 0;
      if (tid == 0) biasPad[t * 8 + d] = 0.f;
      return;
    }
    __shared__ __align__(16) float z[128];
    __shared__ float rc[128], rs[128];
    float zi = logits[((size_t)tid * NTREES + t) * 6 + d];
    z[tid] = zi;
    __syncthreads();
    float k = 0.f, Ssum = 0.f;
    const float4* z4 = (const float4*)z;
    #pragma unroll 4
    for (int q = 0; q < 32; ++q) {
      float4 v = z4[q];
      if (v.x >= zi) { k += 1.f; Ssum += v.x; }
      if (v.y >= zi) { k += 1.f; Ssum += v.y; }
      if (v.z >= zi) { k += 1.f; Ssum += v.z; }
      if (v.w >= zi) { k += 1.f; Ssum += v.w; }
    }
    bool sup = (1.f + k * zi) > Ssum;
    rc[tid] = sup ? 1.f : 0.f;
    rs[tid] = sup ? zi : 0.f;
    __syncthreads();
    for (int off = 64; off > 0; off >>= 1) {
      if (tid < off) { rc[tid] += rc[tid + off]; rs[tid] += rs[tid + off]; }
      __syncthreads();
    }
    float tau = (rs[0] - 1.f) / rc[0];
    float et = expf(-logtemp[t*6 + d]);
    Wfrag[wi] = f2bf(fmaxf(zi - tau, 0.f) * et);
    if (tid == 0) biasPad[t*8 + d] = -thr[t*6 + d] * et;
  } else if (b < 12288) {
    const int r = b - 4096;
    float v = inputs[(size_t)r * DIM + tid];
    int col = ((tid * 2) ^ ((r & 7) << 4)) >> 1;
    Ximg[(size_t)r * DIM + col] = f2bf(v);
  } else {
    const int idx = (b - 12288) * 128 + tid;         // < 524288
    const int j = idx & 7, lane = (idx >> 3) & 63;
    const int ks = (idx >> 9) & 3, half = (idx >> 11) & 1, S = idx >> 12;
    const int G = lane >> 4, u = lane & 15;
    const int tree = S * 4 + G;
    const int leaf = j | (ks << 3) | (half << 5);
    float v = (u < UNITS) ? resp[((size_t)tree*UNITS + u)*64 + leaf] : 0.f;
    Rb[idx] = f2bf(v);
  }
}

// ---------------------------------------------------------------------------
// Main: 2 row-blocks (128 rows) x 32 trees per block, 4 waves, grid 1024.
// tb = (wg&7)*2 + ((wg>>3)&1) -> each XCD owns 2 tree-blocks.  Per sub the
// Afr/B2 fragment loads are shared by BOTH row-blocks (halved L2 stream vs
// the 64-tree round-8 layout).  VGPR ~84 (measured r12) -> (256,4): LDS
// 33.8KB <= 40KB, 4 blocks/CU, grid 1024 = one fully-resident round.
// ---------------------------------------------------------------------------
__global__ __launch_bounds__(256, 4) void odt_main(
    const unsigned short* __restrict__ Ximg, const unsigned short* __restrict__ Wfrag,
    const float* __restrict__ biasPad, const unsigned short* __restrict__ Rb,
    float* __restrict__ partial)
{
  __shared__ __align__(16) char pool[33792];
  char* Xl = pool;                        // 32768 B (2 row-block tiles)
  float* biasl = (float*)(pool + 32768);  // 1024 B (256 floats)
  float* red   = (float*)pool;            // aliases Xl after compute (8 KB)

  const int tid = threadIdx.x;
  const int lane = tid & 63;
  const int w = tid >> 6;       // wave 0..3
  const int G = lane >> 4;      // 0..3 == this lane's tree within the quad
  const int ln = lane & 15;

  const int wg = blockIdx.x;
  const int tb  = (wg & 7) * 2 + ((wg >> 3) & 1);   // 0..15, XCD-grouped
  const int bxg = wg >> 4;                          // 0..63
  const int bx0 = bxg * 2;

  // stage both X tiles (32KB, already bf16+swizzled in Ximg, contiguous)
  {
    const float4* src = (const float4*)(Ximg + (size_t)bx0 * RB * DIM);
    float4* dst = (float4*)Xl;
    #pragma unroll
    for (int it = 0; it < 8; ++it) dst[tid + it * 256] = src[tid + it * 256];
  }
  biasl[tid & 255] = biasPad[(size_t)tb * 256 + (tid & 255)];
  __syncthreads();

  // swizzled X read addresses ((nt*16+ln)&7 == ln&7); tile offset added later
  const char* xbase[4];
  #pragma unroll
  for (int ks = 0; ks < 4; ++ks)
    xbase[ks] = Xl + ln*256 + ((ks*64 + G*16) ^ ((ln & 7) << 4));

  f32x4 out_[2][4];
  #pragma unroll
  for (int bxq = 0; bxq < 2; ++bxq)
    #pragma unroll
    for (int nt = 0; nt < 4; ++nt)
      #pragma unroll
      for (int r = 0; r < 4; ++r) out_[bxq][nt][r] = 0.f;

  const f32x2 ch = (f32x2){0.5f, -0.5f};

  #pragma unroll 1
  for (int sub = 0; sub < 2; ++sub) {
    const int S = tb*8 + sub*4 + w;
    const bf16x8* wf = (const bf16x8*)Wfrag + (size_t)S * 8 * 64;
    const bf16x8* rb = (const bf16x8*)Rb   + (size_t)S * 8 * 64;
    bf16x8 Afr[2][4], B2[2][4];
    #pragma unroll
    for (int p = 0; p < 2; ++p)
      #pragma unroll
      for (int ks = 0; ks < 4; ++ks) {
        Afr[p][ks] = wf[(p*4 + ks)*64 + lane];
        B2[p][ks]  = rb[(p*4 + ks)*64 + lane];
      }
    const int tl8 = ((sub*4 + w)*4 + G) * 8;
    f32x2 bb[6];
    #pragma unroll
    for (int d = 0; d < 6; ++d) {
      float bvd = biasl[tl8 + d];
      bb[d] = (f32x2){0.5f + 0.5f*bvd, 0.5f - 0.5f*bvd};
    }

    #pragma unroll
    for (int bxq = 0; bxq < 2; ++bxq) {
      #pragma unroll
      for (int nt = 0; nt < 4; ++nt) {
        bf16x8 Bfr[4];
        #pragma unroll
        for (int ks = 0; ks < 4; ++ks)
          Bfr[ks] = *(const bf16x8*)(xbase[ks] + bxq*16384 + nt*4096);
        f32x4 c1[2];
        #pragma unroll
        for (int p = 0; p < 2; ++p)
          #pragma unroll
          for (int r = 0; r < 4; ++r) c1[p][r] = 0.f;
        #pragma unroll
        for (int ks = 0; ks < 4; ++ks)
          c1[0] = __builtin_amdgcn_mfma_f32_16x16x32_bf16(Afr[0][ks], Bfr[ks], c1[0], 0,0,0);
        #pragma unroll
        for (int ks = 0; ks < 4; ++ks)
          c1[1] = __builtin_amdgcn_mfma_f32_16x16x32_bf16(Afr[1][ks], Bfr[ks], c1[1], 0,0,0);

        // gates as {s, om} pairs: P = clamp01(fd*{0.5,-0.5} + bb)
        f32x2 P[6];
        #pragma unroll
        for (int d = 0; d < 6; ++d) {
          float fdv = (d < 4) ? c1[0][d] : c1[1][d-4];
          f32x2 t = fdv*ch + bb[d];
          P[d] = __builtin_elementwise_min(
                   __builtin_elementwise_max(t, (f32x2)0.f), (f32x2)1.f);
        }
        // leaf bits: j->d0-2, ks&1->d3, ks>>1->d4, half->d5
        f32x2 qA = P[0]*P[1][0], qB = P[0]*P[1][1];
        f32x2 p3a = qA*P[2][0], p3b = qB*P[2][0];
        f32x2 p3c = qA*P[2][1], p3d = qB*P[2][1];
        f32x2 c34A = P[3]*P[4][0];
        f32x2 c34B = P[3]*P[4][1];

        #pragma unroll
        for (int h = 0; h < 2; ++h) {
          f32x2 ccA = c34A*P[5][h], ccB = c34B*P[5][h];
          float cc[4] = { ccA[0], ccA[1], ccB[0], ccB[1] };
          #pragma unroll
          for (int ks = 0; ks < 4; ++ks) {
            float c = cc[ks];
            u32x4 aw;
            aw[0] = cvtpk(p3a*c);
            aw[1] = cvtpk(p3b*c);
            aw[2] = cvtpk(p3c*c);
            aw[3] = cvtpk(p3d*c);
            bf16x8 A = __builtin_bit_cast(bf16x8, aw);
            out_[bxq][nt] = __builtin_amdgcn_mfma_f32_16x16x32_bf16(A, B2[h][ks], out_[bxq][nt], 0,0,0);
          }
        }
      }
    }
  }

  // ---- cross-wave reduction per row-block (red aliases Xl; Xl dead) ----
  #pragma unroll
  for (int bxq = 0; bxq < 2; ++bxq) {
    __syncthreads();
    if (ln < UNITS) {
      #pragma unroll
      for (int nt = 0; nt < 4; ++nt)
        #pragma unroll
        for (int r = 0; r < 4; ++r)
          red[w*512 + (nt*16 + 4*G + r)*8 + ln] = out_[bxq][nt][r];
    }
    __syncthreads();
    #pragma unroll
    for (int v = 0; v < 2; ++v) {
      int e = tid + v*256;             // 0..511 = row*8+u
      float sum = red[0*512 + e] + red[1*512 + e]
                + red[2*512 + e] + red[3*512 + e];
      partial[((size_t)tb*128 + bx0 + bxq)*512 + e] = sum;
    }
  }
}

// ---------------------------------------------------------------------------
// reduce over the 16 tree-blocks (float4-vectorized), scale by 1/512
// ---------------------------------------------------------------------------
__global__ __launch_bounds__(256) void odt_reduce(
    const f32x4* __restrict__ partial, f32x4* __restrict__ out)
{
  int i = blockIdx.x*256 + threadIdx.x;   // 0..16383 (x4 floats)
  f32x4 sv;
  #pragma unroll
  for (int r = 0; r < 4; ++r) sv[r] = 0.f;
  #pragma unroll
  for (int t = 0; t < NTB; ++t) {
    f32x4 v = partial[(size_t)t * (BATCH*UNITS/4/2) * 2 + i];
    #pragma unroll
    for (int r = 0; r < 4; ++r) sv[r] += v[r];
  }
  #pragma unroll
  for (int r = 0; r < 4; ++r) sv[r] *= (1.f/NTREES);
  out[i] = sv;
}

extern "C" void kernel_launch(void* const* d_in, const int* in_sizes, int n_in,
                              void* d_out, int out_size, void* d_ws, size_t ws_size,
                              hipStream_t stream)
{
  const float* inputs   = (const float*)d_in[0];
  const float* logits   = (const float*)d_in[1];
  const float* thr      = (const float*)d_in[2];
  const float* logtemp  = (const float*)d_in[3];
  const float* response = (const float*)d_in[4];
  float* out = (float*)d_out;

  char* ws = (char*)d_ws;
  unsigned short* Wfrag = (unsigned short*)(ws);                // 1 MB
  unsigned short* Ximg  = (unsigned short*)(ws + (1<<20));      // 2 MB
  unsigned short* Rb    = (unsigned short*)(ws + (3<<20));      // 1 MB
  float* biasPad        = (float*)(ws + (4<<20));               // 16 KB
  float* partial        = (float*)(ws + (4<<20) + (1<<15));     // 4 MB

  hipLaunchKernelGGL(prep_all, dim3(16384), dim3(128), 0, stream,
                     logits, thr, logtemp, inputs, response,
                     Wfrag, Ximg, Rb, biasPad);
  hipLaunchKernelGGL(odt_main, dim3(NTB * NBXG), dim3(256), 0, stream,
                     Ximg, Wfrag, biasPad, Rb, partial);
  hipLaunchKernelGGL(odt_reduce, dim3(BATCH * UNITS / 4 / 256), dim3(256), 0, stream,
                     (const f32x4*)partial, (f32x4*)out);
}

// Round 14
// 46.352 us; speedup vs baseline: 2.1240x; 1.1763x over previous
//
#include <hip/hip_runtime.h>
#include <math.h>

#define BATCH  8192
#define DIM    128
#define NTREES 512
#define UNITS  8
#define RB 64                      // batch rows per row-block
#define NTB 16                     // tree-blocks of 32 trees
#define NBXG 64                    // bx-groups of 2 row-blocks

typedef __attribute__((ext_vector_type(8))) __bf16 bf16x8;
typedef __attribute__((ext_vector_type(4))) float f32x4;
typedef __attribute__((ext_vector_type(2))) float f32x2;
typedef __attribute__((ext_vector_type(4))) unsigned int u32x4;

static __device__ inline unsigned short f2bf(float v) {
  __bf16 h = (__bf16)v;
  return *(unsigned short*)&h;
}

// pack two f32 -> one dword of 2 bf16 (src0 -> [15:0], src1 -> [31:16])
static __device__ inline unsigned cvtpk(f32x2 v) {
  unsigned r;
  asm("v_cvt_pk_bf16_f32 %0, %1, %2" : "=v"(r) : "v"(v[0]), "v"(v[1]));
  return r;
}

// ---------------------------------------------------------------------------
// Fused prep (identical numerics to rounds 8-13):
//  [0,4096):     sparsemax per (tree,d) -> Wfrag A-fragment stream (S = t>>2)
//  [4096,12288): inputs -> bf16 row-swizzled Ximg
//  [12288,16384): response -> Rb B-fragment stream
// ---------------------------------------------------------------------------
__global__ __launch_bounds__(128) void prep_all(
    const float* __restrict__ logits, const float* __restrict__ thr,
    const float* __restrict__ logtemp, const float* __restrict__ inputs,
    const float* __restrict__ resp,
    unsigned short* __restrict__ Wfrag, unsigned short* __restrict__ Ximg,
    unsigned short* __restrict__ Rb, float* __restrict__ biasPad)
{
  const int b = blockIdx.x, tid = threadIdx.x;
  if (b < 4096) {
    const int t = b >> 3, d = b & 7;
    const int S = t >> 2, tq = t & 3;
    const int p = d >> 2, dloc = d & 3;
    const int ln = tq * 4 + dloc;
    const int ks = tid >> 5, G = (tid >> 3) & 3, j = tid & 7;
    const int lane = G * 16 + ln;
    const size_t wi = ((size_t)((S * 2 + p) * 4 + ks) * 64 + lane) * 8 + j;
    if (d >= 6) {
      Wfrag[wi] = 0;
      if (tid == 0) biasPad[t * 8 + d] = 0.f;
      return;
    }
    __shared__ __align__(16) float z[128];
    __shared__ float rc[128], rs[128];
    float zi = logits[((size_t)tid * NTREES + t) * 6 + d];
    z[tid] = zi;
    __syncthreads();
    float k = 0.f, Ssum = 0.f;
    const float4* z4 = (const float4*)z;
    #pragma unroll 4
    for (int q = 0; q < 32; ++q) {
      float4 v = z4[q];
      if (v.x >= zi) { k += 1.f; Ssum += v.x; }
      if (v.y >= zi) { k += 1.f; Ssum += v.y; }
      if (v.z >= zi) { k += 1.f; Ssum += v.z; }
      if (v.w >= zi) { k += 1.f; Ssum += v.w; }
    }
    bool sup = (1.f + k * zi) > Ssum;
    rc[tid] = sup ? 1.f : 0.f;
    rs[tid] = sup ? zi : 0.f;
    __syncthreads();
    for (int off = 64; off > 0; off >>= 1) {
      if (tid < off) { rc[tid] += rc[tid + off]; rs[tid] += rs[tid + off]; }
      __syncthreads();
    }
    float tau = (rs[0] - 1.f) / rc[0];
    float et = expf(-logtemp[t*6 + d]);
    Wfrag[wi] = f2bf(fmaxf(zi - tau, 0.f) * et);
    if (tid == 0) biasPad[t*8 + d] = -thr[t*6 + d] * et;
  } else if (b < 12288) {
    const int r = b - 4096;
    float v = inputs[(size_t)r * DIM + tid];
    int col = ((tid * 2) ^ ((r & 7) << 4)) >> 1;
    Ximg[(size_t)r * DIM + col] = f2bf(v);
  } else {
    const int idx = (b - 12288) * 128 + tid;         // < 524288
    const int j = idx & 7, lane = (idx >> 3) & 63;
    const int ks = (idx >> 9) & 3, half = (idx >> 11) & 1, S = idx >> 12;
    const int G = lane >> 4, u = lane & 15;
    const int tree = S * 4 + G;
    const int leaf = j | (ks << 3) | (half << 5);
    float v = (u < UNITS) ? resp[((size_t)tree*UNITS + u)*64 + leaf] : 0.f;
    Rb[idx] = f2bf(v);
  }
}

// ---------------------------------------------------------------------------
// Main: 2 row-blocks (128 rows) x 32 trees per block, 4 waves, grid 1024.
// tb = (wg&7)*2 + ((wg>>3)&1) -> each XCD owns 2 tree-blocks.  Per sub the
// Afr/B2 fragment loads are shared by BOTH row-blocks (halved L2 stream).
// launch_bounds(256,3): r12 measured this structure at VGPR=84 spill-free;
// (256,4) forced the 64-reg bin and spilled 64 MB (r13).  3 blocks/CU.
// ---------------------------------------------------------------------------
__global__ __launch_bounds__(256, 3) void odt_main(
    const unsigned short* __restrict__ Ximg, const unsigned short* __restrict__ Wfrag,
    const float* __restrict__ biasPad, const unsigned short* __restrict__ Rb,
    float* __restrict__ partial)
{
  __shared__ __align__(16) char pool[33792];
  char* Xl = pool;                        // 32768 B (2 row-block tiles)
  float* biasl = (float*)(pool + 32768);  // 1024 B (256 floats)
  float* red   = (float*)pool;            // aliases Xl after compute (8 KB)

  const int tid = threadIdx.x;
  const int lane = tid & 63;
  const int w = tid >> 6;       // wave 0..3
  const int G = lane >> 4;      // 0..3 == this lane's tree within the quad
  const int ln = lane & 15;

  const int wg = blockIdx.x;
  const int tb  = (wg & 7) * 2 + ((wg >> 3) & 1);   // 0..15, XCD-grouped
  const int bxg = wg >> 4;                          // 0..63
  const int bx0 = bxg * 2;

  // stage both X tiles (32KB, already bf16+swizzled in Ximg, contiguous)
  {
    const float4* src = (const float4*)(Ximg + (size_t)bx0 * RB * DIM);
    float4* dst = (float4*)Xl;
    #pragma unroll
    for (int it = 0; it < 8; ++it) dst[tid + it * 256] = src[tid + it * 256];
  }
  biasl[tid & 255] = biasPad[(size_t)tb * 256 + (tid & 255)];
  __syncthreads();

  // swizzled X read addresses ((nt*16+ln)&7 == ln&7); tile offset added later
  const char* xbase[4];
  #pragma unroll
  for (int ks = 0; ks < 4; ++ks)
    xbase[ks] = Xl + ln*256 + ((ks*64 + G*16) ^ ((ln & 7) << 4));

  f32x4 out_[2][4];
  #pragma unroll
  for (int bxq = 0; bxq < 2; ++bxq)
    #pragma unroll
    for (int nt = 0; nt < 4; ++nt)
      #pragma unroll
      for (int r = 0; r < 4; ++r) out_[bxq][nt][r] = 0.f;

  const f32x2 ch = (f32x2){0.5f, -0.5f};

  #pragma unroll 1
  for (int sub = 0; sub < 2; ++sub) {
    const int S = tb*8 + sub*4 + w;
    const bf16x8* wf = (const bf16x8*)Wfrag + (size_t)S * 8 * 64;
    const bf16x8* rb = (const bf16x8*)Rb   + (size_t)S * 8 * 64;
    bf16x8 Afr[2][4], B2[2][4];
    #pragma unroll
    for (int p = 0; p < 2; ++p)
      #pragma unroll
      for (int ks = 0; ks < 4; ++ks) {
        Afr[p][ks] = wf[(p*4 + ks)*64 + lane];
        B2[p][ks]  = rb[(p*4 + ks)*64 + lane];
      }
    const int tl8 = ((sub*4 + w)*4 + G) * 8;
    f32x2 bb[6];
    #pragma unroll
    for (int d = 0; d < 6; ++d) {
      float bvd = biasl[tl8 + d];
      bb[d] = (f32x2){0.5f + 0.5f*bvd, 0.5f - 0.5f*bvd};
    }

    #pragma unroll
    for (int bxq = 0; bxq < 2; ++bxq) {
      #pragma unroll
      for (int nt = 0; nt < 4; ++nt) {
        bf16x8 Bfr[4];
        #pragma unroll
        for (int ks = 0; ks < 4; ++ks)
          Bfr[ks] = *(const bf16x8*)(xbase[ks] + bxq*16384 + nt*4096);
        f32x4 c1[2];
        #pragma unroll
        for (int p = 0; p < 2; ++p)
          #pragma unroll
          for (int r = 0; r < 4; ++r) c1[p][r] = 0.f;
        #pragma unroll
        for (int ks = 0; ks < 4; ++ks)
          c1[0] = __builtin_amdgcn_mfma_f32_16x16x32_bf16(Afr[0][ks], Bfr[ks], c1[0], 0,0,0);
        #pragma unroll
        for (int ks = 0; ks < 4; ++ks)
          c1[1] = __builtin_amdgcn_mfma_f32_16x16x32_bf16(Afr[1][ks], Bfr[ks], c1[1], 0,0,0);

        // gates as {s, om} pairs: P = clamp01(fd*{0.5,-0.5} + bb)
        f32x2 P[6];
        #pragma unroll
        for (int d = 0; d < 6; ++d) {
          float fdv = (d < 4) ? c1[0][d] : c1[1][d-4];
          f32x2 t = fdv*ch + bb[d];
          P[d] = __builtin_elementwise_min(
                   __builtin_elementwise_max(t, (f32x2)0.f), (f32x2)1.f);
        }
        // leaf bits: j->d0-2, ks&1->d3, ks>>1->d4, half->d5
        f32x2 qA = P[0]*P[1][0], qB = P[0]*P[1][1];
        f32x2 p3a = qA*P[2][0], p3b = qB*P[2][0];
        f32x2 p3c = qA*P[2][1], p3d = qB*P[2][1];
        f32x2 c34A = P[3]*P[4][0];
        f32x2 c34B = P[3]*P[4][1];

        #pragma unroll
        for (int h = 0; h < 2; ++h) {
          f32x2 ccA = c34A*P[5][h], ccB = c34B*P[5][h];
          float cc[4] = { ccA[0], ccA[1], ccB[0], ccB[1] };
          #pragma unroll
          for (int ks = 0; ks < 4; ++ks) {
            float c = cc[ks];
            u32x4 aw;
            aw[0] = cvtpk(p3a*c);
            aw[1] = cvtpk(p3b*c);
            aw[2] = cvtpk(p3c*c);
            aw[3] = cvtpk(p3d*c);
            bf16x8 A = __builtin_bit_cast(bf16x8, aw);
            out_[bxq][nt] = __builtin_amdgcn_mfma_f32_16x16x32_bf16(A, B2[h][ks], out_[bxq][nt], 0,0,0);
          }
        }
      }
    }
  }

  // ---- cross-wave reduction per row-block (red aliases Xl; Xl dead) ----
  #pragma unroll
  for (int bxq = 0; bxq < 2; ++bxq) {
    __syncthreads();
    if (ln < UNITS) {
      #pragma unroll
      for (int nt = 0; nt < 4; ++nt)
        #pragma unroll
        for (int r = 0; r < 4; ++r)
          red[w*512 + (nt*16 + 4*G + r)*8 + ln] = out_[bxq][nt][r];
    }
    __syncthreads();
    #pragma unroll
    for (int v = 0; v < 2; ++v) {
      int e = tid + v*256;             // 0..511 = row*8+u
      float sum = red[0*512 + e] + red[1*512 + e]
                + red[2*512 + e] + red[3*512 + e];
      partial[((size_t)tb*128 + bx0 + bxq)*512 + e] = sum;
    }
  }
}

// ---------------------------------------------------------------------------
// reduce over the 16 tree-blocks (float4-vectorized), scale by 1/512
// ---------------------------------------------------------------------------
__global__ __launch_bounds__(256) void odt_reduce(
    const f32x4* __restrict__ partial, f32x4* __restrict__ out)
{
  int i = blockIdx.x*256 + threadIdx.x;   // 0..16383 (x4 floats)
  f32x4 sv;
  #pragma unroll
  for (int r = 0; r < 4; ++r) sv[r] = 0.f;
  #pragma unroll
  for (int t = 0; t < NTB; ++t) {
    f32x4 v = partial[(size_t)t * (BATCH*UNITS/4/2) * 2 + i];
    #pragma unroll
    for (int r = 0; r < 4; ++r) sv[r] += v[r];
  }
  #pragma unroll
  for (int r = 0; r < 4; ++r) sv[r] *= (1.f/NTREES);
  out[i] = sv;
}

extern "C" void kernel_launch(void* const* d_in, const int* in_sizes, int n_in,
                              void* d_out, int out_size, void* d_ws, size_t ws_size,
                              hipStream_t stream)
{
  const float* inputs   = (const float*)d_in[0];
  const float* logits   = (const float*)d_in[1];
  const float* thr      = (const float*)d_in[2];
  const float* logtemp  = (const float*)d_in[3];
  const float* response = (const float*)d_in[4];
  float* out = (float*)d_out;

  char* ws = (char*)d_ws;
  unsigned short* Wfrag = (unsigned short*)(ws);                // 1 MB
  unsigned short* Ximg  = (unsigned short*)(ws + (1<<20));      // 2 MB
  unsigned short* Rb    = (unsigned short*)(ws + (3<<20));      // 1 MB
  float* biasPad        = (float*)(ws + (4<<20));               // 16 KB
  float* partial        = (float*)(ws + (4<<20) + (1<<15));     // 4 MB

  hipLaunchKernelGGL(prep_all, dim3(16384), dim3(128), 0, stream,
                     logits, thr, logtemp, inputs, response,
                     Wfrag, Ximg, Rb, biasPad);
  hipLaunchKernelGGL(odt_main, dim3(NTB * NBXG), dim3(256), 0, stream,
                     Ximg, Wfrag, biasPad, Rb, partial);
  hipLaunchKernelGGL(odt_reduce, dim3(BATCH * UNITS / 4 / 256), dim3(256), 0, stream,
                     (const f32x4*)partial, (f32x4*)out);
}

// Round 16
// 44.208 us; speedup vs baseline: 2.2270x; 1.0485x over previous
//
#include <hip/hip_runtime.h>
#include <math.h>

#define BATCH  8192
#define DIM    128
#define NTREES 512
#define UNITS  8
#define RB 64                      // batch rows per row-block
#define NTB 16                     // tree-blocks of 32 trees
#define NBXG 64                    // bx-groups of 2 row-blocks

typedef __attribute__((ext_vector_type(8))) __bf16 bf16x8;
typedef __attribute__((ext_vector_type(4))) float f32x4;
typedef __attribute__((ext_vector_type(2))) float f32x2;
typedef __attribute__((ext_vector_type(4))) unsigned int u32x4;

static __device__ inline unsigned short f2bf(float v) {
  __bf16 h = (__bf16)v;
  return *(unsigned short*)&h;
}

// pack two f32 -> one dword of 2 bf16 (src0 -> [15:0], src1 -> [31:16])
static __device__ inline unsigned cvtpk(f32x2 v) {
  unsigned r;
  asm("v_cvt_pk_bf16_f32 %0, %1, %2" : "=v"(r) : "v"(v[0]), "v"(v[1]));
  return r;
}

// ---------------------------------------------------------------------------
// Fused prep (identical numerics to rounds 8-14):
//  [0,4096):     sparsemax per (tree,d) -> Wfrag A-fragment stream (S = t>>2)
//  [4096,12288): inputs -> bf16 row-swizzled Ximg
//  [12288,16384): response -> Rb B-fragment stream
// ---------------------------------------------------------------------------
__global__ __launch_bounds__(128) void prep_all(
    const float* __restrict__ logits, const float* __restrict__ thr,
    const float* __restrict__ logtemp, const float* __restrict__ inputs,
    const float* __restrict__ resp,
    unsigned short* __restrict__ Wfrag, unsigned short* __restrict__ Ximg,
    unsigned short* __restrict__ Rb, float* __restrict__ biasPad)
{
  const int b = blockIdx.x, tid = threadIdx.x;
  if (b < 4096) {
    const int t = b >> 3, d = b & 7;
    const int S = t >> 2, tq = t & 3;
    const int p = d >> 2, dloc = d & 3;
    const int ln = tq * 4 + dloc;
    const int ks = tid >> 5, G = (tid >> 3) & 3, j = tid & 7;
    const int lane = G * 16 + ln;
    const size_t wi = ((size_t)((S * 2 + p) * 4 + ks) * 64 + lane) * 8 + j;
    if (d >= 6) {
      Wfrag[wi] = 0;
      if (tid == 0) biasPad[t * 8 + d] = 0.f;
      return;
    }
    __shared__ __align__(16) float z[128];
    __shared__ float rc[128], rs[128];
    float zi = logits[((size_t)tid * NTREES + t) * 6 + d];
    z[tid] = zi;
    __syncthreads();
    float k = 0.f, Ssum = 0.f;
    const float4* z4 = (const float4*)z;
    #pragma unroll 4
    for (int q = 0; q < 32; ++q) {
      float4 v = z4[q];
      if (v.x >= zi) { k += 1.f; Ssum += v.x; }
      if (v.y >= zi) { k += 1.f; Ssum += v.y; }
      if (v.z >= zi) { k += 1.f; Ssum += v.z; }
      if (v.w >= zi) { k += 1.f; Ssum += v.w; }
    }
    bool sup = (1.f + k * zi) > Ssum;
    rc[tid] = sup ? 1.f : 0.f;
    rs[tid] = sup ? zi : 0.f;
    __syncthreads();
    for (int off = 64; off > 0; off >>= 1) {
      if (tid < off) { rc[tid] += rc[tid + off]; rs[tid] += rs[tid + off]; }
      __syncthreads();
    }
    float tau = (rs[0] - 1.f) / rc[0];
    float et = expf(-logtemp[t*6 + d]);
    Wfrag[wi] = f2bf(fmaxf(zi - tau, 0.f) * et);
    if (tid == 0) biasPad[t*8 + d] = -thr[t*6 + d] * et;
  } else if (b < 12288) {
    const int r = b - 4096;
    float v = inputs[(size_t)r * DIM + tid];
    int col = ((tid * 2) ^ ((r & 7) << 4)) >> 1;
    Ximg[(size_t)r * DIM + col] = f2bf(v);
  } else {
    const int idx = (b - 12288) * 128 + tid;         // < 524288
    const int j = idx & 7, lane = (idx >> 3) & 63;
    const int ks = (idx >> 9) & 3, half = (idx >> 11) & 1, S = idx >> 12;
    const int G = lane >> 4, u = lane & 15;
    const int tree = S * 4 + G;
    const int leaf = j | (ks << 3) | (half << 5);
    float v = (u < UNITS) ? resp[((size_t)tree*UNITS + u)*64 + leaf] : 0.f;
    Rb[idx] = f2bf(v);
  }
}

// ---------------------------------------------------------------------------
// Main: 2 row-blocks (128 rows) x 32 trees per block, 4 waves, grid 1024.
// Round-14 structure (best measured, 46.35us) + s_setprio(1) around the MFMA
// clusters (T5): waves here are barrier-free and phase-diverse, the regime
// where setprio measured +4-7% (attn m191), not the lockstep-GEMM null.
// ---------------------------------------------------------------------------
__global__ __launch_bounds__(256, 3) void odt_main(
    const unsigned short* __restrict__ Ximg, const unsigned short* __restrict__ Wfrag,
    const float* __restrict__ biasPad, const unsigned short* __restrict__ Rb,
    float* __restrict__ partial)
{
  __shared__ __align__(16) char pool[33792];
  char* Xl = pool;                        // 32768 B (2 row-block tiles)
  float* biasl = (float*)(pool + 32768);  // 1024 B (256 floats)
  float* red   = (float*)pool;            // aliases Xl after compute (8 KB)

  const int tid = threadIdx.x;
  const int lane = tid & 63;
  const int w = tid >> 6;       // wave 0..3
  const int G = lane >> 4;      // 0..3 == this lane's tree within the quad
  const int ln = lane & 15;

  const int wg = blockIdx.x;
  const int tb  = (wg & 7) * 2 + ((wg >> 3) & 1);   // 0..15, XCD-grouped
  const int bxg = wg >> 4;                          // 0..63
  const int bx0 = bxg * 2;

  // stage both X tiles (32KB, already bf16+swizzled in Ximg, contiguous)
  {
    const float4* src = (const float4*)(Ximg + (size_t)bx0 * RB * DIM);
    float4* dst = (float4*)Xl;
    #pragma unroll
    for (int it = 0; it < 8; ++it) dst[tid + it * 256] = src[tid + it * 256];
  }
  biasl[tid & 255] = biasPad[(size_t)tb * 256 + (tid & 255)];
  __syncthreads();

  // swizzled X read addresses ((nt*16+ln)&7 == ln&7); tile offset added later
  const char* xbase[4];
  #pragma unroll
  for (int ks = 0; ks < 4; ++ks)
    xbase[ks] = Xl + ln*256 + ((ks*64 + G*16) ^ ((ln & 7) << 4));

  f32x4 out_[2][4];
  #pragma unroll
  for (int bxq = 0; bxq < 2; ++bxq)
    #pragma unroll
    for (int nt = 0; nt < 4; ++nt)
      #pragma unroll
      for (int r = 0; r < 4; ++r) out_[bxq][nt][r] = 0.f;

  const f32x2 ch = (f32x2){0.5f, -0.5f};

  #pragma unroll 1
  for (int sub = 0; sub < 2; ++sub) {
    const int S = tb*8 + sub*4 + w;
    const bf16x8* wf = (const bf16x8*)Wfrag + (size_t)S * 8 * 64;
    const bf16x8* rb = (const bf16x8*)Rb   + (size_t)S * 8 * 64;
    bf16x8 Afr[2][4], B2[2][4];
    #pragma unroll
    for (int p = 0; p < 2; ++p)
      #pragma unroll
      for (int ks = 0; ks < 4; ++ks) {
        Afr[p][ks] = wf[(p*4 + ks)*64 + lane];
        B2[p][ks]  = rb[(p*4 + ks)*64 + lane];
      }
    const int tl8 = ((sub*4 + w)*4 + G) * 8;
    f32x2 bb[6];
    #pragma unroll
    for (int d = 0; d < 6; ++d) {
      float bvd = biasl[tl8 + d];
      bb[d] = (f32x2){0.5f + 0.5f*bvd, 0.5f - 0.5f*bvd};
    }

    #pragma unroll
    for (int bxq = 0; bxq < 2; ++bxq) {
      #pragma unroll
      for (int nt = 0; nt < 4; ++nt) {
        bf16x8 Bfr[4];
        #pragma unroll
        for (int ks = 0; ks < 4; ++ks)
          Bfr[ks] = *(const bf16x8*)(xbase[ks] + bxq*16384 + nt*4096);
        f32x4 c1[2];
        #pragma unroll
        for (int p = 0; p < 2; ++p)
          #pragma unroll
          for (int r = 0; r < 4; ++r) c1[p][r] = 0.f;
        __builtin_amdgcn_s_setprio(1);
        #pragma unroll
        for (int ks = 0; ks < 4; ++ks)
          c1[0] = __builtin_amdgcn_mfma_f32_16x16x32_bf16(Afr[0][ks], Bfr[ks], c1[0], 0,0,0);
        #pragma unroll
        for (int ks = 0; ks < 4; ++ks)
          c1[1] = __builtin_amdgcn_mfma_f32_16x16x32_bf16(Afr[1][ks], Bfr[ks], c1[1], 0,0,0);
        __builtin_amdgcn_s_setprio(0);

        // gates as {s, om} pairs: P = clamp01(fd*{0.5,-0.5} + bb)
        f32x2 P[6];
        #pragma unroll
        for (int d = 0; d < 6; ++d) {
          float fdv = (d < 4) ? c1[0][d] : c1[1][d-4];
          f32x2 t = fdv*ch + bb[d];
          P[d] = __builtin_elementwise_min(
                   __builtin_elementwise_max(t, (f32x2)0.f), (f32x2)1.f);
        }
        // leaf bits: j->d0-2, ks&1->d3, ks>>1->d4, half->d5
        f32x2 qA = P[0]*P[1][0], qB = P[0]*P[1][1];
        f32x2 p3a = qA*P[2][0], p3b = qB*P[2][0];
        f32x2 p3c = qA*P[2][1], p3d = qB*P[2][1];
        f32x2 c34A = P[3]*P[4][0];
        f32x2 c34B = P[3]*P[4][1];

        #pragma unroll
        for (int h = 0; h < 2; ++h) {
          f32x2 ccA = c34A*P[5][h], ccB = c34B*P[5][h];
          float cc[4] = { ccA[0], ccA[1], ccB[0], ccB[1] };
          __builtin_amdgcn_s_setprio(1);
          #pragma unroll
          for (int ks = 0; ks < 4; ++ks) {
            float c = cc[ks];
            u32x4 aw;
            aw[0] = cvtpk(p3a*c);
            aw[1] = cvtpk(p3b*c);
            aw[2] = cvtpk(p3c*c);
            aw[3] = cvtpk(p3d*c);
            bf16x8 A = __builtin_bit_cast(bf16x8, aw);
            out_[bxq][nt] = __builtin_amdgcn_mfma_f32_16x16x32_bf16(A, B2[h][ks], out_[bxq][nt], 0,0,0);
          }
          __builtin_amdgcn_s_setprio(0);
        }
      }
    }
  }

  // ---- cross-wave reduction per row-block (red aliases Xl; Xl dead) ----
  #pragma unroll
  for (int bxq = 0; bxq < 2; ++bxq) {
    __syncthreads();
    if (ln < UNITS) {
      #pragma unroll
      for (int nt = 0; nt < 4; ++nt)
        #pragma unroll
        for (int r = 0; r < 4; ++r)
          red[w*512 + (nt*16 + 4*G + r)*8 + ln] = out_[bxq][nt][r];
    }
    __syncthreads();
    #pragma unroll
    for (int v = 0; v < 2; ++v) {
      int e = tid + v*256;             // 0..511 = row*8+u
      float sum = red[0*512 + e] + red[1*512 + e]
                + red[2*512 + e] + red[3*512 + e];
      partial[((size_t)tb*128 + bx0 + bxq)*512 + e] = sum;
    }
  }
}

// ---------------------------------------------------------------------------
// reduce over the 16 tree-blocks (float4-vectorized), scale by 1/512
// ---------------------------------------------------------------------------
__global__ __launch_bounds__(256) void odt_reduce(
    const f32x4* __restrict__ partial, f32x4* __restrict__ out)
{
  int i = blockIdx.x*256 + threadIdx.x;   // 0..16383 (x4 floats)
  f32x4 sv;
  #pragma unroll
  for (int r = 0; r < 4; ++r) sv[r] = 0.f;
  #pragma unroll
  for (int t = 0; t < NTB; ++t) {
    f32x4 v = partial[(size_t)t * (BATCH*UNITS/4/2) * 2 + i];
    #pragma unroll
    for (int r = 0; r < 4; ++r) sv[r] += v[r];
  }
  #pragma unroll
  for (int r = 0; r < 4; ++r) sv[r] *= (1.f/NTREES);
  out[i] = sv;
}

extern "C" void kernel_launch(void* const* d_in, const int* in_sizes, int n_in,
                              void* d_out, int out_size, void* d_ws, size_t ws_size,
                              hipStream_t stream)
{
  const float* inputs   = (const float*)d_in[0];
  const float* logits   = (const float*)d_in[1];
  const float* thr      = (const float*)d_in[2];
  const float* logtemp  = (const float*)d_in[3];
  const float* response = (const float*)d_in[4];
  float* out = (float*)d_out;

  char* ws = (char*)d_ws;
  unsigned short* Wfrag = (unsigned short*)(ws);                // 1 MB
  unsigned short* Ximg  = (unsigned short*)(ws + (1<<20));      // 2 MB
  unsigned short* Rb    = (unsigned short*)(ws + (3<<20));      // 1 MB
  float* biasPad        = (float*)(ws + (4<<20));               // 16 KB
  float* partial        = (float*)(ws + (4<<20) + (1<<15));     // 4 MB

  hipLaunchKernelGGL(prep_all, dim3(16384), dim3(128), 0, stream,
                     logits, thr, logtemp, inputs, response,
                     Wfrag, Ximg, Rb, biasPad);
  hipLaunchKernelGGL(odt_main, dim3(NTB * NBXG), dim3(256), 0, stream,
                     Ximg, Wfrag, biasPad, Rb, partial);
  hipLaunchKernelGGL(odt_reduce, dim3(BATCH * UNITS / 4 / 256), dim3(256), 0, stream,
                     (const f32x4*)partial, (f32x4*)out);
}